// Round 2
// baseline (149.008 us; speedup 1.0000x reference)
//
#include <hip/hip_runtime.h>
#include <math.h>
#include <stdint.h>

// HungarianMatcher cost matrix: C[n, t] = 5*L1(mid) + 2*focal_class + 5*(L1(head)+L1(tip))
// N = bs*nq = 28800 rows, T = 960 targets, nc = 2 classes. Output 110.6 MB, write-BW bound.
//
// v2 theory: previous 16-rows-per-block LDS design stalled at ~2 TB/s writes while the
// harness fill proves 6.46 TB/s on the same buffer. This version is shape-identical to
// the fill: phase A precomputes 8-float row descriptors into d_ws (transcendentals once
// per row); phase B is a flat 1D stream — one thread = one output float4, globally
// contiguous nt stores, no LDS, no barriers, no idle lanes.

#define BLOCK 256

typedef float f32x4 __attribute__((ext_vector_type(4)));

__device__ __forceinline__ float class_cost(float l) {
    float p  = 1.0f / (1.0f + expf(-l));
    float om = 1.0f - p;
    float pos = om * om * (-logf(p + 1e-8f));
    float neg = p * p * (-logf(om + 1e-8f));   // -log(1 - p + eps)
    return 2.0f * (pos - neg);                  // pre-scaled by COST_CLASS
}

// ---- Phase A: per-row descriptor {hx,hy,tx,ty, mx,my, cc0,cc1} -> ws[N][8] ----
__global__ __launch_bounds__(BLOCK) void row_desc_kernel(
    const float* __restrict__ logits,   // [N,2]
    const float* __restrict__ pscrews,  // [N,4]
    float*       __restrict__ ws,       // [N,8]
    int N)
{
    int n = blockIdx.x * BLOCK + threadIdx.x;
    if (n >= N) return;
    float4 s = reinterpret_cast<const float4*>(pscrews)[n];
    float2 l = reinterpret_cast<const float2*>(logits)[n];
    f32x4 d0 = {s.x, s.y, s.z, s.w};
    f32x4 d1 = {(s.x + s.z) * 0.5f, (s.y + s.w) * 0.5f, class_cost(l.x), class_cost(l.y)};
    f32x4* w = reinterpret_cast<f32x4*>(ws) + (size_t)n * 2;
    w[0] = d0;   // regular stores: ws wants to stay L2-resident for phase B
    w[1] = d1;
}

// ---- Phase B: flat stream. g -> (row = g/TQ, chunk = g%TQ); one f32x4 out per thread ----
__global__ __launch_bounds__(BLOCK) void stream_kernel(
    const float* __restrict__ ws,       // [N,8]
    const int*   __restrict__ tlabels,  // [T]
    const float* __restrict__ tscrews,  // [T,4]
    float*       __restrict__ out,      // [N,T]
    unsigned total, unsigned TQ, unsigned long long M)  // row = (g*M)>>38
{
    unsigned g = blockIdx.x * BLOCK + threadIdx.x;
    if (g >= total) return;
    unsigned row   = (unsigned)(((unsigned long long)g * M) >> 38);
    unsigned chunk = g - row * TQ;

    f32x4 a = reinterpret_cast<const f32x4*>(ws)[(size_t)row * 2 + 0];  // hx,hy,tx,ty
    f32x4 b = reinterpret_cast<const f32x4*>(ws)[(size_t)row * 2 + 1];  // mx,my,cc0,cc1
    int4 lb = reinterpret_cast<const int4*>(tlabels)[chunk];
    int labs[4] = {lb.x, lb.y, lb.z, lb.w};

    float v[4];
    #pragma unroll
    for (int j = 0; j < 4; ++j) {
        float4 s = reinterpret_cast<const float4*>(tscrews)[(size_t)chunk * 4 + j];
        float tmx = (s.x + s.z) * 0.5f;
        float tmy = (s.y + s.w) * 0.5f;
        float d = fabsf(a.x - s.x) + fabsf(a.y - s.y)
                + fabsf(a.z - s.z) + fabsf(a.w - s.w)
                + fabsf(b.x - tmx) + fabsf(b.y - tmy);
        float cc = (labs[j] != 0) ? b.w : b.z;
        v[j] = fmaf(d, 5.0f, cc);
    }
    f32x4 res = {v[0], v[1], v[2], v[3]};
    __builtin_nontemporal_store(res, reinterpret_cast<f32x4*>(out) + g);
}

// ---- Fallback (ws too small): fused recompute per thread, same flat shape ----
__global__ __launch_bounds__(BLOCK) void fused_kernel(
    const float* __restrict__ logits,
    const float* __restrict__ pscrews,
    const int*   __restrict__ tlabels,
    const float* __restrict__ tscrews,
    float*       __restrict__ out,
    unsigned total, unsigned TQ, unsigned long long M)
{
    unsigned g = blockIdx.x * BLOCK + threadIdx.x;
    if (g >= total) return;
    unsigned row   = (unsigned)(((unsigned long long)g * M) >> 38);
    unsigned chunk = g - row * TQ;

    float4 s0 = reinterpret_cast<const float4*>(pscrews)[row];
    float2 l  = reinterpret_cast<const float2*>(logits)[row];
    float mx = (s0.x + s0.z) * 0.5f, my = (s0.y + s0.w) * 0.5f;
    float cc0 = class_cost(l.x), cc1 = class_cost(l.y);

    int4 lb = reinterpret_cast<const int4*>(tlabels)[chunk];
    int labs[4] = {lb.x, lb.y, lb.z, lb.w};

    float v[4];
    #pragma unroll
    for (int j = 0; j < 4; ++j) {
        float4 s = reinterpret_cast<const float4*>(tscrews)[(size_t)chunk * 4 + j];
        float tmx = (s.x + s.z) * 0.5f;
        float tmy = (s.y + s.w) * 0.5f;
        float d = fabsf(s0.x - s.x) + fabsf(s0.y - s.y)
                + fabsf(s0.z - s.z) + fabsf(s0.w - s.w)
                + fabsf(mx - tmx) + fabsf(my - tmy);
        float cc = (labs[j] != 0) ? cc1 : cc0;
        v[j] = fmaf(d, 5.0f, cc);
    }
    f32x4 res = {v[0], v[1], v[2], v[3]};
    __builtin_nontemporal_store(res, reinterpret_cast<f32x4*>(out) + g);
}

extern "C" void kernel_launch(void* const* d_in, const int* in_sizes, int n_in,
                              void* d_out, int out_size, void* d_ws, size_t ws_size,
                              hipStream_t stream) {
    const float* logits  = (const float*)d_in[0];   // [bs, nq, 2]
    const float* pscrews = (const float*)d_in[1];   // [bs, nq, 4]
    const int*   tlabels = (const int*)d_in[2];     // [T]
    const float* tscrews = (const float*)d_in[3];   // [T, 4]
    float* out = (float*)d_out;

    const int N = in_sizes[1] / 4;   // bs*nq = 28800
    const int T = in_sizes[2];       // total targets = 960
    const unsigned TQ = (unsigned)(T / 4);            // float4 chunks per row (240)
    const unsigned total = (unsigned)N * TQ;          // output float4 count (6.912M)
    // magic for row = g / TQ:  M = ceil(2^38 / TQ); exact for g < 2^38/TQ (>> total)
    const unsigned long long M = ((1ULL << 38) + TQ - 1) / TQ;

    const int blocksB = (int)((total + BLOCK - 1) / BLOCK);   // 27000

    if (ws_size >= (size_t)N * 8 * sizeof(float)) {
        const int blocksA = (N + BLOCK - 1) / BLOCK;          // 113
        row_desc_kernel<<<blocksA, BLOCK, 0, stream>>>(logits, pscrews, (float*)d_ws, N);
        stream_kernel<<<blocksB, BLOCK, 0, stream>>>((const float*)d_ws, tlabels, tscrews,
                                                     out, total, TQ, M);
    } else {
        fused_kernel<<<blocksB, BLOCK, 0, stream>>>(logits, pscrews, tlabels, tscrews,
                                                    out, total, TQ, M);
    }
}

// Round 3
// 130.092 us; speedup vs baseline: 1.1454x; 1.1454x over previous
//
#include <hip/hip_runtime.h>
#include <math.h>
#include <stdint.h>

// HungarianMatcher cost matrix: C[n, t] = 5*L1(mid) + 2*focal_class + 5*(L1(head)+L1(tip))
// N = bs*nq = 28800, T = 960. Output 110.6 MB, write-BW bound (fill proves 6.4 TB/s).
//
// v3: keep R0's winning asset (per-thread target data in registers, reused across 16
// rows) but delete the per-block serial structure: no LDS, no barrier, no divergent
// transcendental section. Phase A hoists sigmoid/log focal costs + midpoints into an
// 8-float row descriptor in d_ws; phase B reads descriptors via wave-uniform loads
// (scalarizable to s_load), fully unrolls the 16-row tile in 4-row groups, and issues
// 4 batched nontemporal full-line stores per group.

#define BLOCK 256
#define NB 16

typedef float f32x4 __attribute__((ext_vector_type(4)));

__device__ __forceinline__ float class_cost(float l) {
    float p  = 1.0f / (1.0f + expf(-l));
    float om = 1.0f - p;
    float pos = om * om * (-logf(p + 1e-8f));
    float neg = p * p * (-logf(om + 1e-8f));   // -log(1 - p + eps)
    return 2.0f * (pos - neg);                  // pre-scaled by COST_CLASS
}

// ---- Phase A: per-row descriptor {hx,hy,tx,ty, mx,my, cc0,cc1} -> ws[N][8] ----
__global__ __launch_bounds__(BLOCK) void row_desc_kernel(
    const float* __restrict__ logits,   // [N,2]
    const float* __restrict__ pscrews,  // [N,4]
    float*       __restrict__ ws,       // [N,8]
    int N)
{
    int n = blockIdx.x * BLOCK + threadIdx.x;
    if (n >= N) return;
    float4 s = reinterpret_cast<const float4*>(pscrews)[n];
    float2 l = reinterpret_cast<const float2*>(logits)[n];
    f32x4 d0 = {s.x, s.y, s.z, s.w};
    f32x4 d1 = {(s.x + s.z) * 0.5f, (s.y + s.w) * 0.5f, class_cost(l.x), class_cost(l.y)};
    f32x4* w = reinterpret_cast<f32x4*>(ws) + (size_t)n * 2;
    w[0] = d0;
    w[1] = d1;
}

// ---- Phase B: 16-row tile per block, targets in regs, uniform descriptor loads ----
__global__ __launch_bounds__(BLOCK) void matcher_v3(
    const float* __restrict__ ws,       // [N,8]
    const int*   __restrict__ tlabels,  // [T]
    const float* __restrict__ tscrews,  // [T,4]
    float*       __restrict__ out,      // [N,T]
    int N, int T)
{
    const int tid   = threadIdx.x;
    const int n0    = blockIdx.x * NB;
    const int chunk = tid;                      // 4 targets per thread
    const bool active = (chunk * 4 + 3) < T;    // tid < 240 for T=960

    float thx[4], thy[4], ttx[4], tty[4], tmx[4], tmy[4];
    int   lab[4];
    if (active) {
        int4 lb = reinterpret_cast<const int4*>(tlabels)[chunk];
        lab[0] = lb.x; lab[1] = lb.y; lab[2] = lb.z; lab[3] = lb.w;
        #pragma unroll
        for (int j = 0; j < 4; ++j) {
            float4 s = reinterpret_cast<const float4*>(tscrews)[chunk * 4 + j];
            thx[j] = s.x; thy[j] = s.y; ttx[j] = s.z; tty[j] = s.w;
            tmx[j] = (s.x + s.z) * 0.5f;
            tmy[j] = (s.y + s.w) * 0.5f;
        }
    }
    if (!active) return;

    const int tq = T >> 2;                                   // 240
    f32x4* outv = reinterpret_cast<f32x4*>(out) + (size_t)n0 * tq + chunk;
    const f32x4* w = reinterpret_cast<const f32x4*>(ws) + (size_t)n0 * 2;

    if (n0 + NB <= N) {
        #pragma unroll
        for (int g = 0; g < NB; g += 4) {
            f32x4 res[4];
            #pragma unroll
            for (int r = 0; r < 4; ++r) {
                f32x4 a = w[(g + r) * 2 + 0];   // hx,hy,tx,ty   (wave-uniform)
                f32x4 b = w[(g + r) * 2 + 1];   // mx,my,cc0,cc1 (wave-uniform)
                float v[4];
                #pragma unroll
                for (int j = 0; j < 4; ++j) {
                    float d = fabsf(a.x - thx[j]) + fabsf(a.y - thy[j])
                            + fabsf(a.z - ttx[j]) + fabsf(a.w - tty[j])
                            + fabsf(b.x - tmx[j]) + fabsf(b.y - tmy[j]);
                    float cc = (lab[j] != 0) ? b.w : b.z;
                    v[j] = fmaf(d, 5.0f, cc);
                }
                res[r].x = v[0]; res[r].y = v[1]; res[r].z = v[2]; res[r].w = v[3];
            }
            #pragma unroll
            for (int r = 0; r < 4; ++r) {
                __builtin_nontemporal_store(res[r], outv + (size_t)(g + r) * tq);
            }
        }
    } else {
        for (int r = 0; r < NB; ++r) {
            const int n = n0 + r;
            if (n >= N) break;
            f32x4 a = w[r * 2 + 0];
            f32x4 b = w[r * 2 + 1];
            f32x4 res;
            #pragma unroll
            for (int j = 0; j < 4; ++j) {
                float d = fabsf(a.x - thx[j]) + fabsf(a.y - thy[j])
                        + fabsf(a.z - ttx[j]) + fabsf(a.w - tty[j])
                        + fabsf(b.x - tmx[j]) + fabsf(b.y - tmy[j]);
                float cc = (lab[j] != 0) ? b.w : b.z;
                res[j] = fmaf(d, 5.0f, cc);
            }
            __builtin_nontemporal_store(res, outv + (size_t)r * tq);
        }
    }
}

// ---- Fallback (ws too small): R0-style fused kernel with LDS staging ----
__global__ __launch_bounds__(BLOCK) void matcher_fused(
    const float* __restrict__ logits,
    const float* __restrict__ pscrews,
    const int*   __restrict__ tlabels,
    const float* __restrict__ tscrews,
    float*       __restrict__ out,
    int N, int T)
{
    __shared__ float row[NB][8];
    const int tid = threadIdx.x;
    const int n0  = blockIdx.x * NB;

    if (tid < NB && (n0 + tid) < N) {
        const int n = n0 + tid;
        float4 s = reinterpret_cast<const float4*>(pscrews)[n];
        row[tid][0] = s.x; row[tid][1] = s.y;
        row[tid][2] = s.z; row[tid][3] = s.w;
        row[tid][4] = (s.x + s.z) * 0.5f;
        row[tid][5] = (s.y + s.w) * 0.5f;
        row[tid][6] = class_cost(logits[n * 2 + 0]);
        row[tid][7] = class_cost(logits[n * 2 + 1]);
    }

    const int chunk = tid;
    const bool active = (chunk * 4 + 3) < T;
    float thx[4], thy[4], ttx[4], tty[4], tmx[4], tmy[4];
    int   lab[4];
    if (active) {
        int4 lb = reinterpret_cast<const int4*>(tlabels)[chunk];
        lab[0] = lb.x; lab[1] = lb.y; lab[2] = lb.z; lab[3] = lb.w;
        #pragma unroll
        for (int j = 0; j < 4; ++j) {
            float4 s = reinterpret_cast<const float4*>(tscrews)[chunk * 4 + j];
            thx[j] = s.x; thy[j] = s.y; ttx[j] = s.z; tty[j] = s.w;
            tmx[j] = (s.x + s.z) * 0.5f;
            tmy[j] = (s.y + s.w) * 0.5f;
        }
    }
    __syncthreads();
    if (!active) return;

    const int tq = T >> 2;
    for (int r = 0; r < NB; ++r) {
        const int n = n0 + r;
        if (n >= N) break;
        float4 a = *reinterpret_cast<const float4*>(&row[r][0]);
        float4 b = *reinterpret_cast<const float4*>(&row[r][4]);
        f32x4 res;
        #pragma unroll
        for (int j = 0; j < 4; ++j) {
            float d = fabsf(a.x - thx[j]) + fabsf(a.y - thy[j])
                    + fabsf(a.z - ttx[j]) + fabsf(a.w - tty[j])
                    + fabsf(b.x - tmx[j]) + fabsf(b.y - tmy[j]);
            float cc = (lab[j] != 0) ? b.w : b.z;
            res[j] = fmaf(d, 5.0f, cc);
        }
        __builtin_nontemporal_store(res, reinterpret_cast<f32x4*>(out) + (size_t)n * tq + chunk);
    }
}

extern "C" void kernel_launch(void* const* d_in, const int* in_sizes, int n_in,
                              void* d_out, int out_size, void* d_ws, size_t ws_size,
                              hipStream_t stream) {
    const float* logits  = (const float*)d_in[0];   // [bs, nq, 2]
    const float* pscrews = (const float*)d_in[1];   // [bs, nq, 4]
    const int*   tlabels = (const int*)d_in[2];     // [T]
    const float* tscrews = (const float*)d_in[3];   // [T, 4]
    float* out = (float*)d_out;

    const int N = in_sizes[1] / 4;   // bs*nq = 28800
    const int T = in_sizes[2];       // total targets = 960

    const int blocksB = (N + NB - 1) / NB;          // 1800

    if (ws_size >= (size_t)N * 8 * sizeof(float)) {
        const int blocksA = (N + BLOCK - 1) / BLOCK;    // 113
        row_desc_kernel<<<blocksA, BLOCK, 0, stream>>>(logits, pscrews, (float*)d_ws, N);
        matcher_v3<<<blocksB, BLOCK, 0, stream>>>((const float*)d_ws, tlabels, tscrews,
                                                  out, N, T);
    } else {
        matcher_fused<<<blocksB, BLOCK, 0, stream>>>(logits, pscrews, tlabels, tscrews,
                                                     out, N, T);
    }
}

// Round 4
// 129.064 us; speedup vs baseline: 1.1545x; 1.0080x over previous
//
#include <hip/hip_runtime.h>
#include <math.h>
#include <stdint.h>

// HungarianMatcher cost matrix: C[n, t] = 5*L1(mid) + 2*focal_class + 5*(L1(head)+L1(tip))
// N = bs*nq = 28800, T = 960. Output 110.6 MB, write-BW bound (fill proves 6.46 TB/s).
//
// v4: fill-shaped store stream with sound loads. R0/R1/R3 (block-tiled, 16 rows/block)
// all converge at ~57 µs kernel (~2 TB/s writes); the harness fill hits 6.46 TB/s on the
// same buffer. Last structural difference: the fill is a long-lived grid-stride kernel
// walking the buffer linearly. This version replicates that shape:
//   - phase A: 8-float row descriptors (focal costs, midpoints) into d_ws
//   - phase B: 2048 blocks (8/CU, resident all dispatch), grid-stride over output
//     float4s in linear order; target table in LDS, j-interleaved (tA[j][chunk]) so
//     ds_read_b128 is 16B-lane-stride conflict-free; labels as int4 per chunk.

#define BLOCK 256
#define MAXC  256   // max target chunks staged in LDS (supports T <= 1024)

typedef float f32x4 __attribute__((ext_vector_type(4)));

__device__ __forceinline__ float class_cost(float l) {
    float p  = 1.0f / (1.0f + expf(-l));
    float om = 1.0f - p;
    float pos = om * om * (-logf(p + 1e-8f));
    float neg = p * p * (-logf(om + 1e-8f));   // -log(1 - p + eps)
    return 2.0f * (pos - neg);                  // pre-scaled by COST_CLASS
}

// ---- Phase A: per-row descriptor {hx,hy,tx,ty, mx,my, cc0,cc1} -> ws[N][8] ----
__global__ __launch_bounds__(BLOCK) void row_desc_kernel(
    const float* __restrict__ logits,   // [N,2]
    const float* __restrict__ pscrews,  // [N,4]
    float*       __restrict__ ws,       // [N,8]
    int N)
{
    int n = blockIdx.x * BLOCK + threadIdx.x;
    if (n >= N) return;
    float4 s = reinterpret_cast<const float4*>(pscrews)[n];
    float2 l = reinterpret_cast<const float2*>(logits)[n];
    f32x4 d0 = {s.x, s.y, s.z, s.w};
    f32x4 d1 = {(s.x + s.z) * 0.5f, (s.y + s.w) * 0.5f, class_cost(l.x), class_cost(l.y)};
    f32x4* w = reinterpret_cast<f32x4*>(ws) + (size_t)n * 2;
    w[0] = d0;
    w[1] = d1;
}

// ---- Phase B: grid-stride linear store walk, LDS target table ----
__global__ __launch_bounds__(BLOCK) void stream_lds_kernel(
    const float* __restrict__ ws,       // [N,8]
    const int*   __restrict__ tlabels,  // [T]
    const float* __restrict__ tscrews,  // [T,4]
    float*       __restrict__ out,      // [N,T] viewed as float4[total]
    unsigned total, unsigned TQ, unsigned long long M, int T)
{
    // j-interleaved target table: tA[j][c] = screws of target 4*c+j  (16B lane stride
    // on read -> conflict-free ds_read_b128). tL[c] = labels of targets 4c..4c+3.
    __shared__ float4 tA[4][MAXC];
    __shared__ int4   tL[MAXC];

    for (int t = threadIdx.x; t < T; t += BLOCK) {
        float4 s = reinterpret_cast<const float4*>(tscrews)[t];
        tA[t & 3][t >> 2] = s;
        reinterpret_cast<int*>(tL)[t] = tlabels[t];
    }
    __syncthreads();

    const f32x4* wsv  = reinterpret_cast<const f32x4*>(ws);
    f32x4*       outv = reinterpret_cast<f32x4*>(out);
    const unsigned stride = gridDim.x * BLOCK;

    for (unsigned g = blockIdx.x * BLOCK + threadIdx.x; g < total; g += stride) {
        unsigned row   = (unsigned)(((unsigned long long)g * M) >> 38);  // g / TQ
        unsigned chunk = g - row * TQ;                                   // g % TQ

        f32x4 a = wsv[row * 2 + 0];   // hx,hy,tx,ty   (~wave-uniform, L2-hot)
        f32x4 b = wsv[row * 2 + 1];   // mx,my,cc0,cc1
        int4 lb = tL[chunk];
        int labs[4] = {lb.x, lb.y, lb.z, lb.w};

        float v[4];
        #pragma unroll
        for (int j = 0; j < 4; ++j) {
            float4 s = tA[j][chunk];
            float tmx = (s.x + s.z) * 0.5f;
            float tmy = (s.y + s.w) * 0.5f;
            float d = fabsf(a.x - s.x) + fabsf(a.y - s.y)
                    + fabsf(a.z - s.z) + fabsf(a.w - s.w)
                    + fabsf(b.x - tmx) + fabsf(b.y - tmy);
            float cc = (labs[j] != 0) ? b.w : b.z;
            v[j] = fmaf(d, 5.0f, cc);
        }
        f32x4 res = {v[0], v[1], v[2], v[3]};
        outv[g] = res;   // plain store: byte-order-identical to the fill's linear walk
    }
}

// ---- Fallback (ws too small / T too large): R0-style fused kernel ----
#define NB 16
__global__ __launch_bounds__(BLOCK) void matcher_fused(
    const float* __restrict__ logits,
    const float* __restrict__ pscrews,
    const int*   __restrict__ tlabels,
    const float* __restrict__ tscrews,
    float*       __restrict__ out,
    int N, int T)
{
    __shared__ float row[NB][8];
    const int tid = threadIdx.x;
    const int n0  = blockIdx.x * NB;

    if (tid < NB && (n0 + tid) < N) {
        const int n = n0 + tid;
        float4 s = reinterpret_cast<const float4*>(pscrews)[n];
        row[tid][0] = s.x; row[tid][1] = s.y;
        row[tid][2] = s.z; row[tid][3] = s.w;
        row[tid][4] = (s.x + s.z) * 0.5f;
        row[tid][5] = (s.y + s.w) * 0.5f;
        row[tid][6] = class_cost(logits[n * 2 + 0]);
        row[tid][7] = class_cost(logits[n * 2 + 1]);
    }

    const int chunk = tid;
    const bool active = (chunk * 4 + 3) < T;
    float thx[4], thy[4], ttx[4], tty[4], tmx[4], tmy[4];
    int   lab[4];
    if (active) {
        int4 lb = reinterpret_cast<const int4*>(tlabels)[chunk];
        lab[0] = lb.x; lab[1] = lb.y; lab[2] = lb.z; lab[3] = lb.w;
        #pragma unroll
        for (int j = 0; j < 4; ++j) {
            float4 s = reinterpret_cast<const float4*>(tscrews)[chunk * 4 + j];
            thx[j] = s.x; thy[j] = s.y; ttx[j] = s.z; tty[j] = s.w;
            tmx[j] = (s.x + s.z) * 0.5f;
            tmy[j] = (s.y + s.w) * 0.5f;
        }
    }
    __syncthreads();
    if (!active) return;

    const int tq = T >> 2;
    for (int r = 0; r < NB; ++r) {
        const int n = n0 + r;
        if (n >= N) break;
        float4 a = *reinterpret_cast<const float4*>(&row[r][0]);
        float4 b = *reinterpret_cast<const float4*>(&row[r][4]);
        f32x4 res;
        #pragma unroll
        for (int j = 0; j < 4; ++j) {
            float d = fabsf(a.x - thx[j]) + fabsf(a.y - thy[j])
                    + fabsf(a.z - ttx[j]) + fabsf(a.w - tty[j])
                    + fabsf(b.x - tmx[j]) + fabsf(b.y - tmy[j]);
            float cc = (lab[j] != 0) ? b.w : b.z;
            res[j] = fmaf(d, 5.0f, cc);
        }
        __builtin_nontemporal_store(res, reinterpret_cast<f32x4*>(out) + (size_t)n * tq + chunk);
    }
}

extern "C" void kernel_launch(void* const* d_in, const int* in_sizes, int n_in,
                              void* d_out, int out_size, void* d_ws, size_t ws_size,
                              hipStream_t stream) {
    const float* logits  = (const float*)d_in[0];   // [bs, nq, 2]
    const float* pscrews = (const float*)d_in[1];   // [bs, nq, 4]
    const int*   tlabels = (const int*)d_in[2];     // [T]
    const float* tscrews = (const float*)d_in[3];   // [T, 4]
    float* out = (float*)d_out;

    const int N = in_sizes[1] / 4;   // bs*nq = 28800
    const int T = in_sizes[2];       // total targets = 960

    const bool ws_ok = ws_size >= (size_t)N * 8 * sizeof(float);
    const bool fits  = (T % 4 == 0) && (T / 4 <= MAXC);

    if (ws_ok && fits) {
        const unsigned TQ    = (unsigned)(T / 4);          // 240
        const unsigned total = (unsigned)N * TQ;           // 6,912,000 float4s
        const unsigned long long M = ((1ULL << 38) + TQ - 1) / TQ;  // magic for /TQ

        const int blocksA = (N + BLOCK - 1) / BLOCK;       // 113
        row_desc_kernel<<<blocksA, BLOCK, 0, stream>>>(logits, pscrews, (float*)d_ws, N);

        unsigned need = (total + BLOCK - 1) / BLOCK;
        const int blocksB = (int)(need < 2048u ? need : 2048u);  // 8 blocks/CU resident
        stream_lds_kernel<<<blocksB, BLOCK, 0, stream>>>((const float*)d_ws, tlabels,
                                                         tscrews, out, total, TQ, M, T);
    } else {
        const int blocks = (N + NB - 1) / NB;
        matcher_fused<<<blocks, BLOCK, 0, stream>>>(logits, pscrews, tlabels, tscrews,
                                                    out, N, T);
    }
}